// Round 1
// baseline (190.961 us; speedup 1.0000x reference)
//
#include <hip/hip_runtime.h>
#include <math.h>

#define NN 1024
#define HD 64
#define PD 16
#define BD 8

__device__ __forceinline__ float gelu_tanh(float x) {
    float x3 = x * x * x;
    float inner = 0.7978845608028654f * (x + 0.044715f * x3);
    return 0.5f * x * (1.0f + tanhf(inner));
}

// ---------------- k_h: h[b,i,n] = x[b,0,n]*W0[0,i] + x[b,1,n]*W0[1,i] + b0[i]
__global__ void k_h(const float* __restrict__ x, const float* __restrict__ W0,
                    const float* __restrict__ b0, float* __restrict__ h) {
    int idx = blockIdx.x * blockDim.x + threadIdx.x;  // 524288
    int n = idx & (NN - 1);
    int i = (idx >> 10) & 63;
    int b = idx >> 16;
    float x0 = x[(b * 2 + 0) * NN + n];
    float x1 = x[(b * 2 + 1) * NN + n];
    h[idx] = x0 * W0[i] + x1 * W0[64 + i] + b0[i];
}

// ---------------- k_prep: WA[i,o]=Re(sum_p res), WB[i,o]=Re(sum_p res*pole)
__global__ void k_prep(const float* __restrict__ wp, const float* __restrict__ wpi,
                       const float* __restrict__ wr, const float* __restrict__ wri,
                       float* __restrict__ WA, float* __restrict__ WB) {
    int io = blockIdx.x * blockDim.x + threadIdx.x;  // 4096
    float sa = 0.f, sb = 0.f;
    for (int p = 0; p < PD; ++p) {
        int idx = io * PD + p;
        float rr = wr[idx], ri = wri[idx], pr = wp[idx], pim = wpi[idx];
        sa += rr;
        sb += rr * pr - ri * pim;
    }
    WA[io] = sa;
    WB[io] = sb;
}

// ---------------- FFT helper: in-place radix-2 DIT, input pre-bit-reversed.
// dir = -1 forward, +1 inverse (unscaled). 256 threads.
__device__ void fft_stages(float2* A, float dir) {
    int tid = threadIdx.x;
    for (int s = 1; s <= 10; ++s) {
        int m = 1 << s, half = m >> 1;
        __syncthreads();
        for (int w = tid; w < 512; w += 256) {
            int grp = w >> (s - 1);
            int pos = w & (half - 1);
            int i0 = grp * m + pos;
            int i1 = i0 + half;
            float ang = dir * 6.283185307179586f * (float)pos / (float)m;
            float sn, cs;
            sincosf(ang, &sn, &cs);
            float2 x1 = A[i1];
            float2 t = make_float2(x1.x * cs - x1.y * sn, x1.x * sn + x1.y * cs);
            float2 x0 = A[i0];
            A[i0] = make_float2(x0.x + t.x, x0.y + t.y);
            A[i1] = make_float2(x0.x - t.x, x0.y - t.y);
        }
    }
    __syncthreads();
}

// ---------------- k_fft: per (b,i) row: alpha=FFT(h); u1=IFFT(alpha/lam);
// u2=IFFT(alpha/lam^2); scalars alpha0, A1=N*u1[0](unscaled), A2.
__global__ __launch_bounds__(256) void k_fft(const float* __restrict__ h,
                                             float* __restrict__ u1, float* __restrict__ u2,
                                             float* __restrict__ alpha0,
                                             float* __restrict__ A1v, float* __restrict__ A2v) {
    __shared__ float2 Ab[NN];  // alpha (natural order)
    __shared__ float2 Wb[NN];  // work
    int bi = blockIdx.x;       // b*64+i
    int tid = threadIdx.x;
    const float* row = h + bi * NN;
    for (int j = tid; j < NN; j += 256) {
        int r = __brev((unsigned)j) >> 22;
        Wb[r] = make_float2(row[j], 0.0f);
    }
    fft_stages(Wb, -1.0f);
    for (int j = tid; j < NN; j += 256) Ab[j] = Wb[j];
    __syncthreads();
    if (tid == 0) alpha0[bi] = Ab[0].x;

    // spec1 = alpha * g1, g1 = i*g with g = -1/(2 pi f)   (1/lam, lam=2*pi*i*f)
    for (int j = tid; j < NN; j += 256) {
        int r = __brev((unsigned)j) >> 22;
        float2 v;
        if (j == 0) {
            v = make_float2(0.f, 0.f);
        } else {
            float f = (j < 512) ? (float)j : (float)(j - 1024);
            float g = -1.0f / (6.283185307179586f * f);
            float2 a = Ab[j];
            v = make_float2(-a.y * g, a.x * g);
        }
        Wb[r] = v;
    }
    fft_stages(Wb, +1.0f);
    if (tid == 0) A1v[bi] = Wb[0].x;
    const float invN = 1.0f / (float)NN;
    for (int j = tid; j < NN; j += 256) u1[bi * NN + j] = Wb[j].x * invN;
    __syncthreads();

    // spec2 = alpha * g2, g2 = -1/(4 pi^2 f^2)  (1/lam^2)
    for (int j = tid; j < NN; j += 256) {
        int r = __brev((unsigned)j) >> 22;
        float2 v;
        if (j == 0) {
            v = make_float2(0.f, 0.f);
        } else {
            float f = (j < 512) ? (float)j : (float)(j - 1024);
            float g = -1.0f / (39.47841760435743f * f * f);
            float2 a = Ab[j];
            v = make_float2(a.x * g, a.y * g);
        }
        Wb[r] = v;
    }
    fft_stages(Wb, +1.0f);
    if (tid == 0) A2v[bi] = Wb[0].x;
    for (int j = tid; j < NN; j += 256) u2[bi * NN + j] = Wb[j].x * invN;
}

// ---------------- k_coef: per (b,o): quadratic-in-t coefficients c0,c1,c2
// r2[p] = sum_i [ -res*A1 - (res*pole)*A2 + (res/pole)*alpha0 ]
// c0 = (64*Re(S0) + term0)/N ; c1 = Re(sum_p r2*P1)/N ; c2 = Re(sum_p r2*P2)/(2N)
__global__ void k_coef(const float* __restrict__ wp, const float* __restrict__ wpi,
                       const float* __restrict__ wr, const float* __restrict__ wri,
                       const float* __restrict__ alpha0, const float* __restrict__ A1v,
                       const float* __restrict__ A2v,
                       float* __restrict__ c0, float* __restrict__ c1, float* __restrict__ c2) {
    int bo = blockIdx.x;
    int b = bo >> 6, o = bo & 63;
    int lane = threadIdx.x;
    float r2x = 0.f, r2y = 0.f, P1x = 0.f, P1y = 0.f, P2x = 0.f, P2y = 0.f, t0 = 0.f;
    if (lane < 16) {
        int p = lane;
        for (int i = 0; i < 64; ++i) {
            int idx = (i * 64 + o) * PD + p;
            float rr = wr[idx], ri = wri[idx], pr = wp[idx], pim = wpi[idx];
            float a1 = A1v[b * 64 + i], a2 = A2v[b * 64 + i], a0 = alpha0[b * 64 + i];
            float inv = 1.0f / (pr * pr + pim * pim);
            float ripx = (rr * pr + ri * pim) * inv;  // Re(res/pole)
            float ripy = (ri * pr - rr * pim) * inv;  // Im(res/pole)
            float rpx = rr * pr - ri * pim;           // Re(res*pole)
            float rpy = rr * pim + ri * pr;           // Im(res*pole)
            r2x += -rr * a1 - rpx * a2 + ripx * a0;
            r2y += -ri * a1 - rpy * a2 + ripy * a0;
            P1x += pr;
            P1y += pim;
            P2x += pr * pr - pim * pim;
            P2y += 2.0f * pr * pim;
            t0 += -a0 * ripx;  // alpha0 * Re(K0) contribution
        }
    }
    const float invN = 1.0f / 1024.0f;
    float c0p = (64.0f * r2x + t0) * invN;
    float c1p = (r2x * P1x - r2y * P1y) * invN;
    float c2p = (r2x * P2x - r2y * P2y) * (0.5f * invN);
    for (int off = 8; off >= 1; off >>= 1) {
        c0p += __shfl_down(c0p, off);
        c1p += __shfl_down(c1p, off);
        c2p += __shfl_down(c2p, off);
    }
    if (lane == 0) {
        c0[bo] = c0p;
        c1[bo] = c1p;
        c2[bo] = c2p;
    }
}

// ---------------- k_g: hh[b,o,n] = gelu( sum_i h*Wl + u1*WA + u2*WB + bl
//                                         + c0 + c1*t + c2*t^2 )
// grid 128 blocks: blockIdx>>2 selects 256-element (b,n) chunk; blockIdx&3 = o-slice of 16.
__global__ __launch_bounds__(256) void k_g(const float* __restrict__ h,
                                           const float* __restrict__ u1,
                                           const float* __restrict__ u2,
                                           const float* __restrict__ WA,
                                           const float* __restrict__ WB,
                                           const float* __restrict__ Wl,
                                           const float* __restrict__ bl,
                                           const float* __restrict__ c0,
                                           const float* __restrict__ c1,
                                           const float* __restrict__ c2,
                                           float* __restrict__ hh) {
    __shared__ float sWl[64 * 16], sWA[64 * 16], sWB[64 * 16];
    __shared__ float sbl[16], sc0[16], sc1[16], sc2[16];
    int tid = threadIdx.x;
    int o0 = (blockIdx.x & 3) * 16;
    int g = (blockIdx.x >> 2) * 256 + tid;
    int b = g >> 10;
    int n = g & 1023;
    for (int j = tid; j < 64 * 16; j += 256) {
        int i = j >> 4, oo = j & 15;
        sWl[j] = Wl[i * 64 + o0 + oo];
        sWA[j] = WA[i * 64 + o0 + oo];
        sWB[j] = WB[i * 64 + o0 + oo];
    }
    if (tid < 16) {
        sbl[tid] = bl[o0 + tid];
        sc0[tid] = c0[b * 64 + o0 + tid];
        sc1[tid] = c1[b * 64 + o0 + tid];
        sc2[tid] = c2[b * 64 + o0 + tid];
    }
    __syncthreads();
    float acc[16];
#pragma unroll
    for (int oo = 0; oo < 16; ++oo) acc[oo] = 0.f;
    for (int i = 0; i < 64; ++i) {
        float hv = h[(b * 64 + i) * NN + n];
        float uv1 = u1[(b * 64 + i) * NN + n];
        float uv2 = u2[(b * 64 + i) * NN + n];
#pragma unroll
        for (int oo = 0; oo < 16; ++oo) {
            acc[oo] += hv * sWl[i * 16 + oo] + uv1 * sWA[i * 16 + oo] + uv2 * sWB[i * 16 + oo];
        }
    }
    float t = (float)n * (1.0f / 1023.0f);
    float t2 = t * t;
#pragma unroll
    for (int oo = 0; oo < 16; ++oo) {
        float gg = acc[oo] + sbl[oo] + sc0[oo] + sc1[oo] * t + sc2[oo] * t2;
        hh[(b * 64 + o0 + oo) * NN + n] = gelu_tanh(gg);
    }
}

// ---------------- k_out: out[b,n] = b2 + sum_k gelu( sum_o hh*W1 + b1 ) * W2[k]
__global__ __launch_bounds__(256) void k_out(const float* __restrict__ hh,
                                             const float* __restrict__ W1,
                                             const float* __restrict__ b1,
                                             const float* __restrict__ W2,
                                             const float* __restrict__ b2,
                                             float* __restrict__ out) {
    __shared__ float sW1[4096];
    __shared__ float sb1[64], sW2[64];
    int tid = threadIdx.x;
    int g = blockIdx.x * 256 + tid;
    int b = g >> 10;
    int n = g & 1023;
    for (int j = tid; j < 4096; j += 256) sW1[j] = W1[j];
    if (tid < 64) {
        sb1[tid] = b1[tid];
        sW2[tid] = W2[tid];
    }
    __syncthreads();
    float z[64];
#pragma unroll
    for (int k = 0; k < 64; ++k) z[k] = 0.f;
    for (int o = 0; o < 64; ++o) {
        float hv = hh[(b * 64 + o) * NN + n];
#pragma unroll
        for (int k = 0; k < 64; ++k) z[k] += hv * sW1[o * 64 + k];
    }
    float acc = b2[0];
#pragma unroll
    for (int k = 0; k < 64; ++k) acc += gelu_tanh(z[k] + sb1[k]) * sW2[k];
    out[b * NN + n] = acc;
}

extern "C" void kernel_launch(void* const* d_in, const int* in_sizes, int n_in,
                              void* d_out, int out_size, void* d_ws, size_t ws_size,
                              hipStream_t stream) {
    const float* x = (const float*)d_in[0];
    const float* W0 = (const float*)d_in[1];
    const float* b0 = (const float*)d_in[2];
    const float* wp = (const float*)d_in[3];
    const float* wpi = (const float*)d_in[4];
    const float* wr = (const float*)d_in[5];
    const float* wri = (const float*)d_in[6];
    const float* Wl = (const float*)d_in[7];
    const float* bl = (const float*)d_in[8];
    const float* W1 = (const float*)d_in[9];
    const float* b1 = (const float*)d_in[10];
    const float* W2 = (const float*)d_in[11];
    const float* b2 = (const float*)d_in[12];

    float* ws = (float*)d_ws;
    float* h = ws;                    // 524288
    float* u1 = ws + 524288;          // 524288
    float* u2 = ws + 1048576;         // 524288
    float* hh = ws + 1572864;         // 524288
    float* alpha0 = ws + 2097152;     // 512
    float* A1v = alpha0 + 512;        // 512
    float* A2v = alpha0 + 1024;       // 512
    float* c0 = alpha0 + 1536;        // 512
    float* c1 = alpha0 + 2048;        // 512
    float* c2 = alpha0 + 2560;        // 512
    float* WA = alpha0 + 3072;        // 4096
    float* WB = alpha0 + 3072 + 4096; // 4096

    k_h<<<2048, 256, 0, stream>>>(x, W0, b0, h);
    k_prep<<<16, 256, 0, stream>>>(wp, wpi, wr, wri, WA, WB);
    k_fft<<<512, 256, 0, stream>>>(h, u1, u2, alpha0, A1v, A2v);
    k_coef<<<512, 64, 0, stream>>>(wp, wpi, wr, wri, alpha0, A1v, A2v, c0, c1, c2);
    k_g<<<128, 256, 0, stream>>>(h, u1, u2, WA, WB, Wl, bl, c0, c1, c2, hh);
    k_out<<<32, 256, 0, stream>>>(hh, W1, b1, W2, b2, (float*)d_out);
}

// Round 2
// 130.886 us; speedup vs baseline: 1.4590x; 1.4590x over previous
//
#include <hip/hip_runtime.h>
#include <math.h>

#define NN 1024
#define PD 16

__device__ __forceinline__ float gelu_tanh(float x) {
    float x3 = x * x * x;
    float inner = 0.7978845608028654f * (x + 0.044715f * x3);
    return 0.5f * x * (1.0f + tanhf(inner));
}

// padded float2 index: +1 float2 per 16 to break power-of-2 bank strides
#define PADI(i) ((i) + ((i) >> 4))

// ---------------- DIF forward: natural in, bit-reversed out. A padded, tw[j]=e^{-2pi i j/1024}
__device__ void dif_fft(float2* A, const float2* tw) {
    int tid = threadIdx.x;
    for (int s = 10; s >= 1; --s) {
        int m = 1 << s, half = m >> 1;
        __syncthreads();
        for (int w = tid; w < 512; w += 256) {
            int grp = w >> (s - 1);
            int pos = w & (half - 1);
            int i0 = grp * m + pos;
            int i1 = i0 + half;
            float2 a = A[PADI(i0)];
            float2 b = A[PADI(i1)];
            float2 c = tw[pos << (10 - s)];
            float dx = a.x - b.x, dy = a.y - b.y;
            A[PADI(i0)] = make_float2(a.x + b.x, a.y + b.y);
            A[PADI(i1)] = make_float2(dx * c.x - dy * c.y, dx * c.y + dy * c.x);
        }
    }
    __syncthreads();
}

// ---------------- DIT inverse: bit-reversed in, natural out (unscaled). conj twiddles.
__device__ void dit_ifft(float2* A, const float2* tw) {
    int tid = threadIdx.x;
    for (int s = 1; s <= 10; ++s) {
        int m = 1 << s, half = m >> 1;
        __syncthreads();
        for (int w = tid; w < 512; w += 256) {
            int grp = w >> (s - 1);
            int pos = w & (half - 1);
            int i0 = grp * m + pos;
            int i1 = i0 + half;
            float2 a = A[PADI(i0)];
            float2 b = A[PADI(i1)];
            float2 c = tw[pos << (10 - s)];
            // t = b * conj(c)
            float tx = b.x * c.x + b.y * c.y;
            float ty = b.y * c.x - b.x * c.y;
            A[PADI(i0)] = make_float2(a.x + tx, a.y + ty);
            A[PADI(i1)] = make_float2(a.x - tx, a.y - ty);
        }
    }
    __syncthreads();
}

// ---------------- k_main: per (b,i) row. h computed from x on the fly.
// alpha = FFT(h) (bitrev). u1 = IFFT(alpha/lam), u2 = IFFT(alpha/lam^2).
// Scalars alpha0, A1 (=N*u1[0] unscaled), A2.
__global__ __launch_bounds__(256) void k_main(const float* __restrict__ x,
                                              const float* __restrict__ W0,
                                              const float* __restrict__ b0,
                                              float* __restrict__ u1, float* __restrict__ u2,
                                              float* __restrict__ alpha0,
                                              float* __restrict__ A1v, float* __restrict__ A2v) {
    __shared__ float2 A[NN + (NN >> 4)];  // padded work array
    __shared__ float2 S[NN];              // saved spectrum (bitrev order)
    __shared__ float2 tw[512];            // e^{-2pi i j/N}
    int bi = blockIdx.x;
    int b = bi >> 6, i = bi & 63;
    int tid = threadIdx.x;

    float w00 = W0[i], w01 = W0[64 + i], b0i = b0[i];
    const float4* x0v = (const float4*)(x + b * 2048);
    const float4* x1v = (const float4*)(x + b * 2048 + 1024);
    {
        float4 v0 = x0v[tid];
        float4 v1 = x1v[tid];
        int n0 = tid * 4;
        A[PADI(n0 + 0)] = make_float2(v0.x * w00 + v1.x * w01 + b0i, 0.f);
        A[PADI(n0 + 1)] = make_float2(v0.y * w00 + v1.y * w01 + b0i, 0.f);
        A[PADI(n0 + 2)] = make_float2(v0.z * w00 + v1.z * w01 + b0i, 0.f);
        A[PADI(n0 + 3)] = make_float2(v0.w * w00 + v1.w * w01 + b0i, 0.f);
    }
    for (int j = tid; j < 512; j += 256) {
        float sn, cs;
        sincosf(-6.283185307179586f * (float)j * (1.0f / 1024.0f), &sn, &cs);
        tw[j] = make_float2(cs, sn);
    }

    dif_fft(A, tw);  // has leading+trailing syncs

    for (int r = tid; r < NN; r += 256) S[r] = A[PADI(r)];
    __syncthreads();
    if (tid == 0) alpha0[bi] = S[0].x;

    // spec1 slot r holds freq j=brev(r): *1/lam = -i/(2 pi f)
    for (int r = tid; r < NN; r += 256) {
        int j = __brev((unsigned)r) >> 22;
        float2 v;
        if (j == 0) {
            v = make_float2(0.f, 0.f);
        } else {
            float f = (j < 512) ? (float)j : (float)(j - 1024);
            float w = 6.283185307179586f * f;
            float2 a = S[r];
            v = make_float2(a.y / w, -a.x / w);
        }
        A[PADI(r)] = v;
    }
    dit_ifft(A, tw);
    if (tid == 0) A1v[bi] = A[PADI(0)].x;
    const float invN = 1.0f / (float)NN;
    {
        float* dst = u1 + bi * NN;
        for (int n = tid; n < NN; n += 256) dst[n] = A[PADI(n)].x * invN;
    }
    __syncthreads();

    // spec2: *1/lam^2 = -1/(4 pi^2 f^2)
    for (int r = tid; r < NN; r += 256) {
        int j = __brev((unsigned)r) >> 22;
        float2 v;
        if (j == 0) {
            v = make_float2(0.f, 0.f);
        } else {
            float f = (j < 512) ? (float)j : (float)(j - 1024);
            float g = -1.0f / (39.47841760435743f * f * f);
            float2 a = S[r];
            v = make_float2(a.x * g, a.y * g);
        }
        A[PADI(r)] = v;
    }
    dit_ifft(A, tw);
    if (tid == 0) A2v[bi] = A[PADI(0)].x;
    {
        float* dst = u2 + bi * NN;
        for (int n = tid; n < NN; n += 256) dst[n] = A[PADI(n)].x * invN;
    }
}

// ---------------- k_small: fused prep (WA/WB) + coef (c0,c1,c2).
// One block per o (64 blocks, 256 threads = 16 i4-groups x 16 p).
__global__ __launch_bounds__(256) void k_small(const float* __restrict__ wp,
                                               const float* __restrict__ wpi,
                                               const float* __restrict__ wr,
                                               const float* __restrict__ wri,
                                               const float* __restrict__ alpha0,
                                               const float* __restrict__ A1v,
                                               const float* __restrict__ A2v,
                                               float* __restrict__ WA, float* __restrict__ WB,
                                               float* __restrict__ c0, float* __restrict__ c1,
                                               float* __restrict__ c2) {
    __shared__ float a0s[512], a1s[512], a2s[512];
    __shared__ float wred[4][16][28];  // [wave][p][quantity]
    int o = blockIdx.x;
    int tid = threadIdx.x;
    int p = tid & 15;
    int i4 = tid >> 4;
    for (int t = tid; t < 512; t += 256) {
        a0s[t] = alpha0[t];
        a1s[t] = A1v[t];
        a2s[t] = A2v[t];
    }
    __syncthreads();

    float p1x = 0.f, p1y = 0.f, p2x = 0.f, p2y = 0.f;
    float r2x[8], r2y[8], t0[8];
#pragma unroll
    for (int b = 0; b < 8; ++b) { r2x[b] = 0.f; r2y[b] = 0.f; t0[b] = 0.f; }
    float rrs[4], rpxs[4];

#pragma unroll
    for (int ib = 0; ib < 4; ++ib) {
        int i = ib * 16 + i4;
        int idx = (i * 64 + o) * PD + p;
        float rr = wr[idx], ri = wri[idx], pr = wp[idx], pim = wpi[idx];
        float inv = 1.0f / (pr * pr + pim * pim);
        float ripx = (rr * pr + ri * pim) * inv;  // Re(res/pole)
        float ripy = (ri * pr - rr * pim) * inv;  // Im(res/pole)
        float rpx = rr * pr - ri * pim;           // Re(res*pole)
        float rpy = rr * pim + ri * pr;           // Im(res*pole)
        rrs[ib] = rr;
        rpxs[ib] = rpx;
        p1x += pr; p1y += pim;
        p2x += pr * pr - pim * pim;
        p2y += 2.0f * pr * pim;
#pragma unroll
        for (int b = 0; b < 8; ++b) {
            float a1 = a1s[b * 64 + i], a2 = a2s[b * 64 + i], a0 = a0s[b * 64 + i];
            r2x[b] += -rr * a1 - rpx * a2 + ripx * a0;
            r2y[b] += -ri * a1 - rpy * a2 + ripy * a0;
            t0[b] += -a0 * ripx;
        }
    }

    // WA/WB: reduce rr, rpx over the 16 p-lanes of each i4 group (xor<=8 stays in group)
#pragma unroll
    for (int ib = 0; ib < 4; ++ib) {
        float wa = rrs[ib], wb = rpxs[ib];
        for (int off = 8; off >= 1; off >>= 1) {
            wa += __shfl_xor(wa, off);
            wb += __shfl_xor(wb, off);
        }
        if (p == 0) {
            int i = ib * 16 + i4;
            WA[i * 64 + o] = wa;
            WB[i * 64 + o] = wb;
        }
    }

    // reduce i within wave: lanes l and l+16, l+32, l+48 share p
    float q[28];
    q[0] = p1x; q[1] = p1y; q[2] = p2x; q[3] = p2y;
#pragma unroll
    for (int b = 0; b < 8; ++b) { q[4 + b] = r2x[b]; q[12 + b] = r2y[b]; q[20 + b] = t0[b]; }
#pragma unroll
    for (int k = 0; k < 28; ++k) {
        q[k] += __shfl_down(q[k], 32);
        q[k] += __shfl_down(q[k], 16);
    }
    int lane = tid & 63, wv = tid >> 6;
    if (lane < 16) {
#pragma unroll
        for (int k = 0; k < 28; ++k) wred[wv][lane][k] = q[k];
    }
    __syncthreads();
    if (tid < 16) {
        float s[28];
#pragma unroll
        for (int k = 0; k < 28; ++k)
            s[k] = wred[0][tid][k] + wred[1][tid][k] + wred[2][tid][k] + wred[3][tid][k];
        const float invN = 1.0f / 1024.0f;
        float cc[24];
#pragma unroll
        for (int b = 0; b < 8; ++b) {
            float rx = s[4 + b], ry = s[12 + b];
            cc[b] = (64.0f * rx + s[20 + b]) * invN;
            cc[8 + b] = (rx * s[0] - ry * s[1]) * invN;
            cc[16 + b] = (rx * s[2] - ry * s[3]) * (0.5f * invN);
        }
#pragma unroll
        for (int k = 0; k < 24; ++k) {
            cc[k] += __shfl_xor(cc[k], 1);
            cc[k] += __shfl_xor(cc[k], 2);
            cc[k] += __shfl_xor(cc[k], 4);
            cc[k] += __shfl_xor(cc[k], 8);
        }
        if (tid == 0) {
#pragma unroll
            for (int b = 0; b < 8; ++b) {
                c0[b * 64 + o] = cc[b];
                c1[b * 64 + o] = cc[8 + b];
                c2[b * 64 + o] = cc[16 + b];
            }
        }
    }
}

// ---------------- k_g: hh[b,o,n] = gelu( sum_i h*Wl + u1*WA + u2*WB + bl + c0 + c1 t + c2 t^2 )
// h recomputed from x. 256 blocks: (blockIdx&7)=o-slice of 8, (blockIdx>>3)=chunk of 256 (b,n).
__global__ __launch_bounds__(256) void k_g(const float* __restrict__ x,
                                           const float* __restrict__ W0,
                                           const float* __restrict__ b0,
                                           const float* __restrict__ u1,
                                           const float* __restrict__ u2,
                                           const float* __restrict__ WA,
                                           const float* __restrict__ WB,
                                           const float* __restrict__ Wl,
                                           const float* __restrict__ bl,
                                           const float* __restrict__ c0,
                                           const float* __restrict__ c1,
                                           const float* __restrict__ c2,
                                           float* __restrict__ hh) {
    __shared__ float sWl[64 * 8], sWA[64 * 8], sWB[64 * 8];
    __shared__ float sW0a[64], sW0b[64], sb0v[64];
    __shared__ float sbl[8], sc0[8], sc1[8], sc2[8];
    int tid = threadIdx.x;
    int o0 = (blockIdx.x & 7) * 8;
    int g = (blockIdx.x >> 3) * 256 + tid;
    int b = g >> 10;
    int n = g & 1023;
    for (int j = tid; j < 512; j += 256) {
        int i = j >> 3, oo = j & 7;
        sWl[j] = Wl[i * 64 + o0 + oo];
        sWA[j] = WA[i * 64 + o0 + oo];
        sWB[j] = WB[i * 64 + o0 + oo];
    }
    if (tid < 64) {
        sW0a[tid] = W0[tid];
        sW0b[tid] = W0[64 + tid];
        sb0v[tid] = b0[tid];
    }
    if (tid < 8) {
        sbl[tid] = bl[o0 + tid];
        sc0[tid] = c0[b * 64 + o0 + tid];
        sc1[tid] = c1[b * 64 + o0 + tid];
        sc2[tid] = c2[b * 64 + o0 + tid];
    }
    __syncthreads();
    float x0 = x[b * 2048 + n];
    float x1 = x[b * 2048 + 1024 + n];
    float acc[8];
#pragma unroll
    for (int oo = 0; oo < 8; ++oo) acc[oo] = 0.f;
    for (int i = 0; i < 64; ++i) {
        float hv = x0 * sW0a[i] + x1 * sW0b[i] + sb0v[i];
        float uv1 = u1[(b * 64 + i) * NN + n];
        float uv2 = u2[(b * 64 + i) * NN + n];
#pragma unroll
        for (int oo = 0; oo < 8; ++oo) {
            acc[oo] += hv * sWl[i * 8 + oo] + uv1 * sWA[i * 8 + oo] + uv2 * sWB[i * 8 + oo];
        }
    }
    float t = (float)n * (1.0f / 1023.0f);
    float t2 = t * t;
#pragma unroll
    for (int oo = 0; oo < 8; ++oo) {
        float gg = acc[oo] + sbl[oo] + sc0[oo] + sc1[oo] * t + sc2[oo] * t2;
        hh[(b * 64 + o0 + oo) * NN + n] = gelu_tanh(gg);
    }
}

// ---------------- k_out: split-k. 128 blocks x 256 threads (64 n x 4 k-quarters).
__global__ __launch_bounds__(256) void k_out(const float* __restrict__ hh,
                                             const float* __restrict__ W1,
                                             const float* __restrict__ b1,
                                             const float* __restrict__ W2,
                                             const float* __restrict__ b2,
                                             float* __restrict__ out) {
    __shared__ float sW1[4096];
    __shared__ float sb1[64], sW2[64];
    __shared__ float red[4][64];
    int tid = threadIdx.x;
    int nl = tid & 63;
    int kq = tid >> 6;
    int gg = blockIdx.x * 64 + nl;
    int b = gg >> 10;
    int n = gg & 1023;
    for (int j = tid; j < 4096; j += 256) sW1[j] = W1[j];
    if (tid < 64) {
        sb1[tid] = b1[tid];
        sW2[tid] = W2[tid];
    }
    __syncthreads();
    float z[16];
#pragma unroll
    for (int k = 0; k < 16; ++k) z[k] = 0.f;
    for (int o = 0; o < 64; ++o) {
        float hv = hh[(b * 64 + o) * NN + n];
#pragma unroll
        for (int k = 0; k < 16; ++k) z[k] += hv * sW1[o * 64 + kq * 16 + k];
    }
    float part = 0.f;
#pragma unroll
    for (int k = 0; k < 16; ++k) part += gelu_tanh(z[k] + sb1[kq * 16 + k]) * sW2[kq * 16 + k];
    red[kq][nl] = part;
    __syncthreads();
    if (kq == 0) {
        out[gg] = b2[0] + red[0][nl] + red[1][nl] + red[2][nl] + red[3][nl];
    }
}

extern "C" void kernel_launch(void* const* d_in, const int* in_sizes, int n_in,
                              void* d_out, int out_size, void* d_ws, size_t ws_size,
                              hipStream_t stream) {
    const float* x = (const float*)d_in[0];
    const float* W0 = (const float*)d_in[1];
    const float* b0 = (const float*)d_in[2];
    const float* wp = (const float*)d_in[3];
    const float* wpi = (const float*)d_in[4];
    const float* wr = (const float*)d_in[5];
    const float* wri = (const float*)d_in[6];
    const float* Wl = (const float*)d_in[7];
    const float* bl = (const float*)d_in[8];
    const float* W1 = (const float*)d_in[9];
    const float* b1 = (const float*)d_in[10];
    const float* W2 = (const float*)d_in[11];
    const float* b2 = (const float*)d_in[12];

    float* ws = (float*)d_ws;
    float* u1 = ws;                   // 524288
    float* u2 = ws + 524288;          // 524288
    float* hh = ws + 1048576;         // 524288
    float* alpha0 = ws + 1572864;     // 512
    float* A1v = alpha0 + 512;
    float* A2v = alpha0 + 1024;
    float* c0 = alpha0 + 1536;
    float* c1 = alpha0 + 2048;
    float* c2 = alpha0 + 2560;
    float* WA = alpha0 + 3072;        // 4096
    float* WB = alpha0 + 3072 + 4096; // 4096

    k_main<<<512, 256, 0, stream>>>(x, W0, b0, u1, u2, alpha0, A1v, A2v);
    k_small<<<64, 256, 0, stream>>>(wp, wpi, wr, wri, alpha0, A1v, A2v, WA, WB, c0, c1, c2);
    k_g<<<256, 256, 0, stream>>>(x, W0, b0, u1, u2, WA, WB, Wl, bl, c0, c1, c2, hh);
    k_out<<<128, 256, 0, stream>>>(hh, W1, b1, W2, b2, (float*)d_out);
}

// Round 3
// 110.535 us; speedup vs baseline: 1.7276x; 1.1841x over previous
//
#include <hip/hip_runtime.h>
#include <math.h>

#define NN 1024
#define PD 16

__device__ __forceinline__ float gelu_tanh(float x) {
    float x3 = x * x * x;
    float inner = 0.7978845608028654f * (x + 0.044715f * x3);
    return 0.5f * x * (1.0f + tanhf(inner));
}

// padded float2 index: +1 float2 per 16 to break power-of-2 bank strides
#define PADI(i) ((i) + ((i) >> 4))

// compiler-only memory fence: wave-synchronous LDS comm (DS pipe is in-order
// per wave; 64 lanes lockstep on CDNA) — no s_barrier needed for intra-wave stages
#define WAVE_FENCE() asm volatile("" ::: "memory")

__device__ __forceinline__ void bf_dif(float2* A, const float2* tw, int i0, int i1, int ti) {
    float2 a = A[PADI(i0)];
    float2 b = A[PADI(i1)];
    float2 c = tw[ti];
    float dx = a.x - b.x, dy = a.y - b.y;
    A[PADI(i0)] = make_float2(a.x + b.x, a.y + b.y);
    A[PADI(i1)] = make_float2(dx * c.x - dy * c.y, dx * c.y + dy * c.x);
}

__device__ __forceinline__ void bf_dit(float2* A, const float2* tw, int i0, int i1, int ti) {
    float2 a = A[PADI(i0)];
    float2 b = A[PADI(i1)];
    float2 c = tw[ti];  // conj applied
    float tx = b.x * c.x + b.y * c.y;
    float ty = b.y * c.x - b.x * c.y;
    A[PADI(i0)] = make_float2(a.x + tx, a.y + ty);
    A[PADI(i1)] = make_float2(a.x - tx, a.y - ty);
}

// DIT inverse wave-local stages 1..8, then cross stages 9,10 with barriers.
__device__ __forceinline__ void dit_wave_stages(float2* A, const float2* tw, int lane, int cb) {
#pragma unroll
    for (int s = 1; s <= 8; ++s) {
        int m = 1 << s, half = m >> 1;
#pragma unroll
        for (int k = 0; k < 2; ++k) {
            int lb = lane + k * 64;
            int grp = lb >> (s - 1), pos = lb & (half - 1);
            int i0 = cb + grp * m + pos;
            bf_dit(A, tw, i0, i0 + half, pos << (10 - s));
        }
        WAVE_FENCE();
    }
}

__device__ __forceinline__ void dit_cross_stages(float2* A, const float2* tw, int tid) {
    __syncthreads();
    // s = 9
#pragma unroll
    for (int k = 0; k < 2; ++k) {
        int w = tid + k * 256;
        int grp = w >> 8, pos = w & 255;
        int i0 = grp * 512 + pos;
        bf_dit(A, tw, i0, i0 + 256, pos << 1);
    }
    __syncthreads();
    // s = 10
#pragma unroll
    for (int k = 0; k < 2; ++k) {
        int w = tid + k * 256;
        bf_dit(A, tw, w, w + 512, w);
    }
    __syncthreads();
}

// ---------------- k_main: per (b,i) row: h from x on the fly; alpha=FFT(h) (bitrev);
// u1 = IFFT(alpha/lam); u2 = IFFT(alpha/lam^2); scalars alpha0, A1, A2.
__global__ __launch_bounds__(256) void k_main(const float* __restrict__ x,
                                              const float* __restrict__ W0,
                                              const float* __restrict__ b0,
                                              float* __restrict__ u1, float* __restrict__ u2,
                                              float* __restrict__ alpha0,
                                              float* __restrict__ A1v, float* __restrict__ A2v) {
    __shared__ float2 A[NN + (NN >> 4)];  // padded work array
    __shared__ float2 S[NN];              // saved spectrum (bitrev order)
    __shared__ float2 tw[512];            // e^{-2pi i j/N}
    int bi = blockIdx.x;
    int b = bi >> 6, i = bi & 63;
    int tid = threadIdx.x;
    int lane = tid & 63, wv = tid >> 6, cb = wv << 8;
    int n0 = tid * 4;

    float w00 = W0[i], w01 = W0[64 + i], b0i = b0[i];
    {
        const float4* x0v = (const float4*)(x + b * 2048);
        const float4* x1v = (const float4*)(x + b * 2048 + 1024);
        float4 v0 = x0v[tid];
        float4 v1 = x1v[tid];
        A[PADI(n0 + 0)] = make_float2(v0.x * w00 + v1.x * w01 + b0i, 0.f);
        A[PADI(n0 + 1)] = make_float2(v0.y * w00 + v1.y * w01 + b0i, 0.f);
        A[PADI(n0 + 2)] = make_float2(v0.z * w00 + v1.z * w01 + b0i, 0.f);
        A[PADI(n0 + 3)] = make_float2(v0.w * w00 + v1.w * w01 + b0i, 0.f);
    }
    for (int j = tid; j < 512; j += 256) {
        float sn, cs;
        sincosf(-6.283185307179586f * (float)j * (1.0f / 1024.0f), &sn, &cs);
        tw[j] = make_float2(cs, sn);
    }
    __syncthreads();  // B1

    // ---- forward DIF: s=10, s=9 cross; s=8..1 wave-local
#pragma unroll
    for (int k = 0; k < 2; ++k) {
        int w = tid + k * 256;
        bf_dif(A, tw, w, w + 512, w);
    }
    __syncthreads();  // B2
#pragma unroll
    for (int k = 0; k < 2; ++k) {
        int w = tid + k * 256;
        int grp = w >> 8, pos = w & 255;
        int i0 = grp * 512 + pos;
        bf_dif(A, tw, i0, i0 + 256, pos << 1);
    }
    __syncthreads();  // B3
#pragma unroll
    for (int s = 8; s >= 1; --s) {
        int m = 1 << s, half = m >> 1;
#pragma unroll
        for (int k = 0; k < 2; ++k) {
            int lb = lane + k * 64;
            int grp = lb >> (s - 1), pos = lb & (half - 1);
            int i0 = cb + grp * m + pos;
            bf_dif(A, tw, i0, i0 + half, pos << (10 - s));
        }
        WAVE_FENCE();
    }

    // ---- fused save-spectrum + scale-1 (1/lam): thread-local slots 4t..4t+3
    {
#pragma unroll
        for (int j = 0; j < 4; ++j) {
            int r = n0 + j;
            float2 a = A[PADI(r)];
            S[r] = a;
            if (r == 0) alpha0[bi] = a.x;
            int fj = (int)(__brev((unsigned)r) >> 22);
            float2 v;
            if (fj == 0) {
                v = make_float2(0.f, 0.f);
            } else {
                float f = (fj < 512) ? (float)fj : (float)(fj - 1024);
                float wq = 6.283185307179586f * f;
                v = make_float2(a.y / wq, -a.x / wq);
            }
            A[PADI(r)] = v;
        }
    }
    WAVE_FENCE();

    // ---- inverse DIT #1
    dit_wave_stages(A, tw, lane, cb);
    dit_cross_stages(A, tw, tid);  // internal barriers; ends with barrier

    // ---- store u1 + scale-2 (1/lam^2) into A (same thread-local slots)
    const float invN = 1.0f / (float)NN;
    {
        float2 a0 = A[PADI(n0 + 0)];
        float2 a1 = A[PADI(n0 + 1)];
        float2 a2 = A[PADI(n0 + 2)];
        float2 a3 = A[PADI(n0 + 3)];
        ((float4*)(u1 + bi * NN))[tid] = make_float4(a0.x * invN, a1.x * invN, a2.x * invN, a3.x * invN);
        if (tid == 0) A1v[bi] = a0.x;
#pragma unroll
        for (int j = 0; j < 4; ++j) {
            int r = n0 + j;
            int fj = (int)(__brev((unsigned)r) >> 22);
            float2 v;
            if (fj == 0) {
                v = make_float2(0.f, 0.f);
            } else {
                float f = (fj < 512) ? (float)fj : (float)(fj - 1024);
                float g = -1.0f / (39.47841760435743f * f * f);
                float2 s = S[r];
                v = make_float2(s.x * g, s.y * g);
            }
            A[PADI(r)] = v;
        }
    }
    WAVE_FENCE();

    // ---- inverse DIT #2
    dit_wave_stages(A, tw, lane, cb);
    dit_cross_stages(A, tw, tid);

    {
        float2 a0 = A[PADI(n0 + 0)];
        float2 a1 = A[PADI(n0 + 1)];
        float2 a2 = A[PADI(n0 + 2)];
        float2 a3 = A[PADI(n0 + 3)];
        ((float4*)(u2 + bi * NN))[tid] = make_float4(a0.x * invN, a1.x * invN, a2.x * invN, a3.x * invN);
        if (tid == 0) A2v[bi] = a0.x;
    }
}

// ---------------- k_small: fused prep (WA/WB) + coef (c0,c1,c2). 64 blocks x 256.
__global__ __launch_bounds__(256) void k_small(const float* __restrict__ wp,
                                               const float* __restrict__ wpi,
                                               const float* __restrict__ wr,
                                               const float* __restrict__ wri,
                                               const float* __restrict__ alpha0,
                                               const float* __restrict__ A1v,
                                               const float* __restrict__ A2v,
                                               float* __restrict__ WA, float* __restrict__ WB,
                                               float* __restrict__ c0, float* __restrict__ c1,
                                               float* __restrict__ c2) {
    __shared__ float a0s[512], a1s[512], a2s[512];
    __shared__ float wred[4][16][28];  // [wave][p][quantity]
    int o = blockIdx.x;
    int tid = threadIdx.x;
    int p = tid & 15;
    int i4 = tid >> 4;
    for (int t = tid; t < 512; t += 256) {
        a0s[t] = alpha0[t];
        a1s[t] = A1v[t];
        a2s[t] = A2v[t];
    }
    __syncthreads();

    float p1x = 0.f, p1y = 0.f, p2x = 0.f, p2y = 0.f;
    float r2x[8], r2y[8], t0[8];
#pragma unroll
    for (int b = 0; b < 8; ++b) { r2x[b] = 0.f; r2y[b] = 0.f; t0[b] = 0.f; }
    float rrs[4], rpxs[4];

#pragma unroll
    for (int ib = 0; ib < 4; ++ib) {
        int i = ib * 16 + i4;
        int idx = (i * 64 + o) * PD + p;
        float rr = wr[idx], ri = wri[idx], pr = wp[idx], pim = wpi[idx];
        float inv = 1.0f / (pr * pr + pim * pim);
        float ripx = (rr * pr + ri * pim) * inv;  // Re(res/pole)
        float ripy = (ri * pr - rr * pim) * inv;  // Im(res/pole)
        float rpx = rr * pr - ri * pim;           // Re(res*pole)
        float rpy = rr * pim + ri * pr;           // Im(res*pole)
        rrs[ib] = rr;
        rpxs[ib] = rpx;
        p1x += pr; p1y += pim;
        p2x += pr * pr - pim * pim;
        p2y += 2.0f * pr * pim;
#pragma unroll
        for (int b = 0; b < 8; ++b) {
            float a1 = a1s[b * 64 + i], a2 = a2s[b * 64 + i], a0 = a0s[b * 64 + i];
            r2x[b] += -rr * a1 - rpx * a2 + ripx * a0;
            r2y[b] += -ri * a1 - rpy * a2 + ripy * a0;
            t0[b] += -a0 * ripx;
        }
    }

#pragma unroll
    for (int ib = 0; ib < 4; ++ib) {
        float wa = rrs[ib], wb = rpxs[ib];
        for (int off = 8; off >= 1; off >>= 1) {
            wa += __shfl_xor(wa, off);
            wb += __shfl_xor(wb, off);
        }
        if (p == 0) {
            int i = ib * 16 + i4;
            WA[i * 64 + o] = wa;
            WB[i * 64 + o] = wb;
        }
    }

    float q[28];
    q[0] = p1x; q[1] = p1y; q[2] = p2x; q[3] = p2y;
#pragma unroll
    for (int b = 0; b < 8; ++b) { q[4 + b] = r2x[b]; q[12 + b] = r2y[b]; q[20 + b] = t0[b]; }
#pragma unroll
    for (int k = 0; k < 28; ++k) {
        q[k] += __shfl_down(q[k], 32);
        q[k] += __shfl_down(q[k], 16);
    }
    int lane = tid & 63, wv = tid >> 6;
    if (lane < 16) {
#pragma unroll
        for (int k = 0; k < 28; ++k) wred[wv][lane][k] = q[k];
    }
    __syncthreads();
    if (tid < 16) {
        float s[28];
#pragma unroll
        for (int k = 0; k < 28; ++k)
            s[k] = wred[0][tid][k] + wred[1][tid][k] + wred[2][tid][k] + wred[3][tid][k];
        const float invN = 1.0f / 1024.0f;
        float cc[24];
#pragma unroll
        for (int b = 0; b < 8; ++b) {
            float rx = s[4 + b], ry = s[12 + b];
            cc[b] = (64.0f * rx + s[20 + b]) * invN;
            cc[8 + b] = (rx * s[0] - ry * s[1]) * invN;
            cc[16 + b] = (rx * s[2] - ry * s[3]) * (0.5f * invN);
        }
#pragma unroll
        for (int k = 0; k < 24; ++k) {
            cc[k] += __shfl_xor(cc[k], 1);
            cc[k] += __shfl_xor(cc[k], 2);
            cc[k] += __shfl_xor(cc[k], 4);
            cc[k] += __shfl_xor(cc[k], 8);
        }
        if (tid == 0) {
#pragma unroll
            for (int b = 0; b < 8; ++b) {
                c0[b * 64 + o] = cc[b];
                c1[b * 64 + o] = cc[8 + b];
                c2[b * 64 + o] = cc[16 + b];
            }
        }
    }
}

// ---------------- k_gout: fused k_g + k_out. 256 blocks x 256 threads.
// Block: b = blk>>5, n-slice of 32. Phase A: hh tile (all 64 o) in LDS; Phase B: out.
__global__ __launch_bounds__(256) void k_gout(const float* __restrict__ x,
                                              const float* __restrict__ W0,
                                              const float* __restrict__ b0,
                                              const float* __restrict__ u1,
                                              const float* __restrict__ u2,
                                              const float* __restrict__ WA,
                                              const float* __restrict__ WB,
                                              const float* __restrict__ Wl,
                                              const float* __restrict__ bl,
                                              const float* __restrict__ c0,
                                              const float* __restrict__ c1,
                                              const float* __restrict__ c2,
                                              const float* __restrict__ W1,
                                              const float* __restrict__ b1,
                                              const float* __restrict__ W2,
                                              const float* __restrict__ b2,
                                              float* __restrict__ out) {
    __shared__ float sU1[64 * 32], sU2[64 * 32];                   // [i][n]
    __shared__ float sWl[4096], sWA[4096], sWB[4096], sW1[4096];   // [i][o] / [o][k]
    __shared__ float hhs[64 * 34];                                 // [o][n] pad->34
    __shared__ float sW0a[64], sW0b[64], sb0[64], sbl[64];
    __shared__ float sc0[64], sc1[64], sc2[64], sb1[64], sW2[64];
    __shared__ float red[8 * 32];
    int tid = threadIdx.x;
    int b = blockIdx.x >> 5;
    int n0 = (blockIdx.x & 31) << 5;

    {
        const float4* Wl4 = (const float4*)Wl;
        const float4* WA4 = (const float4*)WA;
        const float4* WB4 = (const float4*)WB;
        const float4* W14 = (const float4*)W1;
        for (int j = tid; j < 1024; j += 256) {
            ((float4*)sWl)[j] = Wl4[j];
            ((float4*)sWA)[j] = WA4[j];
            ((float4*)sWB)[j] = WB4[j];
            ((float4*)sW1)[j] = W14[j];
        }
        const float4* u14 = (const float4*)u1;
        const float4* u24 = (const float4*)u2;
        int nb4 = n0 >> 2;
        for (int j = tid; j < 512; j += 256) {
            int i = j >> 3, c4 = j & 7;
            ((float4*)sU1)[j] = u14[(b * 64 + i) * 256 + nb4 + c4];
            ((float4*)sU2)[j] = u24[(b * 64 + i) * 256 + nb4 + c4];
        }
        if (tid < 64) {
            sW0a[tid] = W0[tid];
            sW0b[tid] = W0[64 + tid];
            sb0[tid] = b0[tid];
            sbl[tid] = bl[tid];
            sc0[tid] = c0[b * 64 + tid];
            sc1[tid] = c1[b * 64 + tid];
            sc2[tid] = c2[b * 64 + tid];
            sb1[tid] = b1[tid];
            sW2[tid] = W2[tid];
        }
    }
    __syncthreads();

    // Phase A: og = tid>>4 (To=4), ng = tid&15 (Tn=2)
    {
        int og = tid >> 4, ng = tid & 15;
        int oB = og * 4, nB = ng * 2;
        float x0a = x[b * 2048 + n0 + nB];
        float x0b = x[b * 2048 + n0 + nB + 1];
        float x1a = x[b * 2048 + 1024 + n0 + nB];
        float x1b = x[b * 2048 + 1024 + n0 + nB + 1];
        float acc0[4], acc1[4];
#pragma unroll
        for (int r = 0; r < 4; ++r) { acc0[r] = 0.f; acc1[r] = 0.f; }
        for (int i = 0; i < 64; ++i) {
            float w0a = sW0a[i], w0b = sW0b[i], bb = sb0[i];
            float hva = x0a * w0a + x1a * w0b + bb;
            float hvb = x0b * w0a + x1b * w0b + bb;
            float2 ua = *(const float2*)&sU1[i * 32 + nB];
            float2 va = *(const float2*)&sU2[i * 32 + nB];
            float4 wl = *(const float4*)&sWl[i * 64 + oB];
            float4 wa = *(const float4*)&sWA[i * 64 + oB];
            float4 wb = *(const float4*)&sWB[i * 64 + oB];
            acc0[0] += hva * wl.x + ua.x * wa.x + va.x * wb.x;
            acc1[0] += hvb * wl.x + ua.y * wa.x + va.y * wb.x;
            acc0[1] += hva * wl.y + ua.x * wa.y + va.x * wb.y;
            acc1[1] += hvb * wl.y + ua.y * wa.y + va.y * wb.y;
            acc0[2] += hva * wl.z + ua.x * wa.z + va.x * wb.z;
            acc1[2] += hvb * wl.z + ua.y * wa.z + va.y * wb.z;
            acc0[3] += hva * wl.w + ua.x * wa.w + va.x * wb.w;
            acc1[3] += hvb * wl.w + ua.y * wa.w + va.y * wb.w;
        }
        float ta = (float)(n0 + nB) * (1.0f / 1023.0f);
        float tb = (float)(n0 + nB + 1) * (1.0f / 1023.0f);
#pragma unroll
        for (int r = 0; r < 4; ++r) {
            int o = oB + r;
            float ga = acc0[r] + sbl[o] + sc0[o] + sc1[o] * ta + sc2[o] * ta * ta;
            float gb = acc1[r] + sbl[o] + sc0[o] + sc1[o] * tb + sc2[o] * tb * tb;
            hhs[o * 34 + nB] = gelu_tanh(ga);
            hhs[o * 34 + nB + 1] = gelu_tanh(gb);
        }
    }
    __syncthreads();

    // Phase B: n = tid&31, kq = tid>>5, k-tile of 8
    {
        int n = tid & 31, kq = tid >> 5;
        float z[8];
#pragma unroll
        for (int k = 0; k < 8; ++k) z[k] = 0.f;
        for (int o = 0; o < 64; ++o) {
            float hv = hhs[o * 34 + n];
            float4 w1a = *(const float4*)&sW1[o * 64 + kq * 8];
            float4 w1b = *(const float4*)&sW1[o * 64 + kq * 8 + 4];
            z[0] += hv * w1a.x; z[1] += hv * w1a.y; z[2] += hv * w1a.z; z[3] += hv * w1a.w;
            z[4] += hv * w1b.x; z[5] += hv * w1b.y; z[6] += hv * w1b.z; z[7] += hv * w1b.w;
        }
        float part = 0.f;
#pragma unroll
        for (int k = 0; k < 8; ++k) part += gelu_tanh(z[k] + sb1[kq * 8 + k]) * sW2[kq * 8 + k];
        red[kq * 32 + n] = part;
    }
    __syncthreads();
    if (tid < 32) {
        float s = red[tid];
#pragma unroll
        for (int k = 1; k < 8; ++k) s += red[k * 32 + tid];
        out[b * 1024 + n0 + tid] = s + b2[0];
    }
}

extern "C" void kernel_launch(void* const* d_in, const int* in_sizes, int n_in,
                              void* d_out, int out_size, void* d_ws, size_t ws_size,
                              hipStream_t stream) {
    const float* x = (const float*)d_in[0];
    const float* W0 = (const float*)d_in[1];
    const float* b0 = (const float*)d_in[2];
    const float* wp = (const float*)d_in[3];
    const float* wpi = (const float*)d_in[4];
    const float* wr = (const float*)d_in[5];
    const float* wri = (const float*)d_in[6];
    const float* Wl = (const float*)d_in[7];
    const float* bl = (const float*)d_in[8];
    const float* W1 = (const float*)d_in[9];
    const float* b1 = (const float*)d_in[10];
    const float* W2 = (const float*)d_in[11];
    const float* b2 = (const float*)d_in[12];

    float* ws = (float*)d_ws;
    float* u1 = ws;                   // 524288
    float* u2 = ws + 524288;          // 524288
    float* alpha0 = ws + 1048576;     // 512
    float* A1v = alpha0 + 512;
    float* A2v = alpha0 + 1024;
    float* c0 = alpha0 + 1536;
    float* c1 = alpha0 + 2048;
    float* c2 = alpha0 + 2560;
    float* WA = alpha0 + 3072;        // 4096
    float* WB = alpha0 + 3072 + 4096; // 4096

    k_main<<<512, 256, 0, stream>>>(x, W0, b0, u1, u2, alpha0, A1v, A2v);
    k_small<<<64, 256, 0, stream>>>(wp, wpi, wr, wri, alpha0, A1v, A2v, WA, WB, c0, c1, c2);
    k_gout<<<256, 256, 0, stream>>>(x, W0, b0, u1, u2, WA, WB, Wl, bl, c0, c1, c2,
                                    W1, b1, W2, b2, (float*)d_out);
}

// Round 5
// 107.873 us; speedup vs baseline: 1.7702x; 1.0247x over previous
//
#include <hip/hip_runtime.h>
#include <math.h>

#define NN 1024
#define PD 16

__device__ __forceinline__ float gelu_tanh(float x) {
    float x3 = x * x * x;
    float inner = 0.7978845608028654f * (x + 0.044715f * x3);
    return 0.5f * x * (1.0f + tanhf(inner));
}

// padded float2 index: +1 float2 per 16 to break power-of-2 bank strides
#define PADI(i) ((i) + ((i) >> 4))

// compiler-only fence: wave-synchronous LDS comm (DS pipe in-order per wave,
// 64 lanes lockstep) — verified correct on this HW in R2/R3.
#define WAVE_FENCE() asm volatile("" ::: "memory")

__device__ __forceinline__ void bf_dif(float2* A, const float2* tw, int i0, int i1, int ti) {
    float2 a = A[PADI(i0)];
    float2 b = A[PADI(i1)];
    float2 c = tw[ti];
    float dx = a.x - b.x, dy = a.y - b.y;
    A[PADI(i0)] = make_float2(a.x + b.x, a.y + b.y);
    A[PADI(i1)] = make_float2(dx * c.x - dy * c.y, dx * c.y + dy * c.x);
}

__device__ __forceinline__ void bf_dit(float2* A, const float2* tw, int i0, int i1, int ti) {
    float2 a = A[PADI(i0)];
    float2 b = A[PADI(i1)];
    float2 c = tw[ti];  // conj applied in-formula
    float tx = b.x * c.x + b.y * c.y;
    float ty = b.y * c.x - b.x * c.y;
    A[PADI(i0)] = make_float2(a.x + tx, a.y + ty);
    A[PADI(i1)] = make_float2(a.x - tx, a.y - ty);
}

// dual-array inverse DIT: wave-local stages 1..8 (fence only), then cross 9,10.
__device__ __forceinline__ void dit_wave_dual(float2* A0, float2* A1, const float2* tw,
                                              int lane, int cb) {
#pragma unroll
    for (int s = 1; s <= 8; ++s) {
        int m = 1 << s, half = m >> 1;
#pragma unroll
        for (int k = 0; k < 2; ++k) {
            int lb = lane + k * 64;
            int grp = lb >> (s - 1), pos = lb & (half - 1);
            int i0 = cb + grp * m + pos;
            int ti = pos << (10 - s);
            bf_dit(A0, tw, i0, i0 + half, ti);
            bf_dit(A1, tw, i0, i0 + half, ti);
        }
        WAVE_FENCE();
    }
}

__device__ __forceinline__ void dit_cross_dual(float2* A0, float2* A1, const float2* tw, int tid) {
    __syncthreads();
#pragma unroll
    for (int k = 0; k < 2; ++k) {
        int w = tid + k * 256;
        int pos = w & 255, i0 = (w >> 8) * 512 + pos;
        bf_dit(A0, tw, i0, i0 + 256, pos << 1);
        bf_dit(A1, tw, i0, i0 + 256, pos << 1);
    }
    __syncthreads();
#pragma unroll
    for (int k = 0; k < 2; ++k) {
        int w = tid + k * 256;
        bf_dit(A0, tw, w, w + 512, w);
        bf_dit(A1, tw, w, w + 512, w);
    }
    __syncthreads();
}

// ---------------- k_main: 256 blocks, 2 rows each via real-packing.
// Z = FFT(h_a + i h_b) (1 fwd FFT). Unpack alpha_a/alpha_b per bin; build
// specA = alpha_a*(m1 + i*m2), specB likewise (m1=1/lam, m2=1/lam^2); two
// packed inverse FFTs give u1+i*u2 for each row. 3 FFTs per 2 rows (was 6).
__global__ __launch_bounds__(256) void k_main(const float* __restrict__ x,
                                              const float* __restrict__ W0,
                                              const float* __restrict__ b0,
                                              float* __restrict__ u1, float* __restrict__ u2,
                                              float* __restrict__ alpha0,
                                              float* __restrict__ A1v, float* __restrict__ A2v) {
    __shared__ float2 A[NN + (NN >> 4)];  // padded work (row a spec / packed u)
    __shared__ float2 B[NN + (NN >> 4)];  // padded work (row b)
    __shared__ float2 Z[NN];              // fwd spectrum, bitrev slots
    __shared__ float2 tw[512];            // e^{-2pi i j/N}
    int blk = blockIdx.x;                 // 0..255
    int bi0 = blk * 2, bi1 = bi0 + 1;
    int b = bi0 >> 6;
    int ia = bi0 & 63, ib = ia + 1;
    int tid = threadIdx.x;
    int lane = tid & 63, wv = tid >> 6, cb = wv << 8;
    int n0 = tid * 4;

    float w00a = W0[ia], w01a = W0[64 + ia], b0a = b0[ia];
    float w00b = W0[ib], w01b = W0[64 + ib], b0b = b0[ib];
    {
        const float4* x0v = (const float4*)(x + b * 2048);
        const float4* x1v = (const float4*)(x + b * 2048 + 1024);
        float4 v0 = x0v[tid];
        float4 v1 = x1v[tid];
        float xe[4] = {v0.x, v0.y, v0.z, v0.w};
        float xo[4] = {v1.x, v1.y, v1.z, v1.w};
#pragma unroll
        for (int j = 0; j < 4; ++j) {
            float hA = xe[j] * w00a + xo[j] * w01a + b0a;
            float hB = xe[j] * w00b + xo[j] * w01b + b0b;
            A[PADI(n0 + j)] = make_float2(hA, hB);  // packed: h_a + i h_b
        }
    }
    for (int j = tid; j < 512; j += 256) {
        float sn, cs;
        sincosf(-6.283185307179586f * (float)j * (1.0f / 1024.0f), &sn, &cs);
        tw[j] = make_float2(cs, sn);
    }
    __syncthreads();  // B1

    // ---- forward DIF (single array): s=10, s=9 cross; s=8..1 wave-local
#pragma unroll
    for (int k = 0; k < 2; ++k) {
        int w = tid + k * 256;
        bf_dif(A, tw, w, w + 512, w);
    }
    __syncthreads();  // B2
#pragma unroll
    for (int k = 0; k < 2; ++k) {
        int w = tid + k * 256;
        int pos = w & 255, i0 = (w >> 8) * 512 + pos;
        bf_dif(A, tw, i0, i0 + 256, pos << 1);
    }
    __syncthreads();  // B3
#pragma unroll
    for (int s = 8; s >= 1; --s) {
        int m = 1 << s, half = m >> 1;
#pragma unroll
        for (int k = 0; k < 2; ++k) {
            int lb = lane + k * 64;
            int grp = lb >> (s - 1), pos = lb & (half - 1);
            int i0 = cb + grp * m + pos;
            bf_dif(A, tw, i0, i0 + half, pos << (10 - s));
        }
        WAVE_FENCE();
    }

    // save Z (wave-local slots), then barrier so cross-wave gathers are safe
#pragma unroll
    for (int j = 0; j < 4; ++j) {
        int r = n0 + j;
        Z[r] = A[PADI(r)];
    }
    if (tid == 0) {
        alpha0[bi0] = Z[0].x;  // alpha_a(0)
        alpha0[bi1] = Z[0].y;  // alpha_b(0)
    }
    __syncthreads();  // B4

    // ---- unpack + combined spectral multiply, thread-local slots
    // alpha_a(k) = (Z(k)+conj(Z(N-k)))/2 ; alpha_b(k) = -i(Z(k)-conj(Z(N-k)))/2
    // M(j) = m1 + i*m2 = -i*(1/w + 1/w^2),  w = 2*pi*f  (f signed)
    // spec = alpha*M = (alpha.y*q, -alpha.x*q), q = 1/w + 1/w^2
#pragma unroll
    for (int j = 0; j < 4; ++j) {
        int r = n0 + j;
        int fj = (int)(__brev((unsigned)r) >> 22);
        if (fj == 0) {
            A[PADI(r)] = make_float2(0.f, 0.f);
            B[PADI(r)] = make_float2(0.f, 0.f);
        } else {
            int jm = (NN - fj) & (NN - 1);
            int rm = (int)(__brev((unsigned)jm) >> 22);
            float2 Zk = Z[r];
            float2 Zm = Z[rm];
            float Cc = Zm.x, Dd = -Zm.y;  // conj(Z(N-k))
            float aax = 0.5f * (Zk.x + Cc), aay = 0.5f * (Zk.y + Dd);
            float abx = 0.5f * (Zk.y - Dd), aby = -0.5f * (Zk.x - Cc);
            float f = (fj < 512) ? (float)fj : (float)(fj - 1024);
            float w = 6.283185307179586f * f;
            float q = 1.0f / w + 1.0f / (w * w);
            A[PADI(r)] = make_float2(aay * q, -aax * q);
            B[PADI(r)] = make_float2(aby * q, -abx * q);
        }
    }
    WAVE_FENCE();

    // ---- dual packed inverse FFT
    dit_wave_dual(A, B, tw, lane, cb);
    dit_cross_dual(A, B, tw, tid);  // trailing barrier

    // ---- outputs: Re -> u1, Im -> u2 for each row
    const float invN = 1.0f / (float)NN;
    {
        float2 a0 = A[PADI(n0 + 0)], a1 = A[PADI(n0 + 1)];
        float2 a2 = A[PADI(n0 + 2)], a3 = A[PADI(n0 + 3)];
        float2 bb0 = B[PADI(n0 + 0)], bb1 = B[PADI(n0 + 1)];
        float2 bb2 = B[PADI(n0 + 2)], bb3 = B[PADI(n0 + 3)];
        ((float4*)(u1 + bi0 * NN))[tid] =
            make_float4(a0.x * invN, a1.x * invN, a2.x * invN, a3.x * invN);
        ((float4*)(u2 + bi0 * NN))[tid] =
            make_float4(a0.y * invN, a1.y * invN, a2.y * invN, a3.y * invN);
        ((float4*)(u1 + bi1 * NN))[tid] =
            make_float4(bb0.x * invN, bb1.x * invN, bb2.x * invN, bb3.x * invN);
        ((float4*)(u2 + bi1 * NN))[tid] =
            make_float4(bb0.y * invN, bb1.y * invN, bb2.y * invN, bb3.y * invN);
        if (tid == 0) {
            A1v[bi0] = a0.x;   // N * u1_a[0]
            A2v[bi0] = a0.y;   // N * u2_a[0]
            A1v[bi1] = bb0.x;
            A2v[bi1] = bb0.y;
        }
    }
}

// ---------------- k_small: fused prep (WA/WB) + coef (c0,c1,c2). 64 blocks x 256.
__global__ __launch_bounds__(256) void k_small(const float* __restrict__ wp,
                                               const float* __restrict__ wpi,
                                               const float* __restrict__ wr,
                                               const float* __restrict__ wri,
                                               const float* __restrict__ alpha0,
                                               const float* __restrict__ A1v,
                                               const float* __restrict__ A2v,
                                               float* __restrict__ WA, float* __restrict__ WB,
                                               float* __restrict__ c0, float* __restrict__ c1,
                                               float* __restrict__ c2) {
    __shared__ float a0s[512], a1s[512], a2s[512];
    __shared__ float wred[4][16][28];  // [wave][p][quantity]
    int o = blockIdx.x;
    int tid = threadIdx.x;
    int p = tid & 15;
    int i4 = tid >> 4;
    for (int t = tid; t < 512; t += 256) {
        a0s[t] = alpha0[t];
        a1s[t] = A1v[t];
        a2s[t] = A2v[t];
    }
    __syncthreads();

    float p1x = 0.f, p1y = 0.f, p2x = 0.f, p2y = 0.f;
    float r2x[8], r2y[8], t0[8];
#pragma unroll
    for (int b = 0; b < 8; ++b) { r2x[b] = 0.f; r2y[b] = 0.f; t0[b] = 0.f; }
    float rrs[4], rpxs[4];

#pragma unroll
    for (int ibl = 0; ibl < 4; ++ibl) {
        int i = ibl * 16 + i4;
        int idx = (i * 64 + o) * PD + p;
        float rr = wr[idx], ri = wri[idx], pr = wp[idx], pim = wpi[idx];
        float inv = 1.0f / (pr * pr + pim * pim);
        float ripx = (rr * pr + ri * pim) * inv;  // Re(res/pole)
        float ripy = (ri * pr - rr * pim) * inv;  // Im(res/pole)
        float rpx = rr * pr - ri * pim;           // Re(res*pole)
        float rpy = rr * pim + ri * pr;           // Im(res*pole)
        rrs[ibl] = rr;
        rpxs[ibl] = rpx;
        p1x += pr; p1y += pim;
        p2x += pr * pr - pim * pim;
        p2y += 2.0f * pr * pim;
#pragma unroll
        for (int b = 0; b < 8; ++b) {
            float a1 = a1s[b * 64 + i], a2 = a2s[b * 64 + i], a0 = a0s[b * 64 + i];
            r2x[b] += -rr * a1 - rpx * a2 + ripx * a0;
            r2y[b] += -ri * a1 - rpy * a2 + ripy * a0;
            t0[b] += -a0 * ripx;
        }
    }

#pragma unroll
    for (int ibl = 0; ibl < 4; ++ibl) {
        float wa = rrs[ibl], wb = rpxs[ibl];
        for (int off = 8; off >= 1; off >>= 1) {
            wa += __shfl_xor(wa, off);
            wb += __shfl_xor(wb, off);
        }
        if (p == 0) {
            int i = ibl * 16 + i4;
            WA[i * 64 + o] = wa;
            WB[i * 64 + o] = wb;
        }
    }

    float q[28];
    q[0] = p1x; q[1] = p1y; q[2] = p2x; q[3] = p2y;
#pragma unroll
    for (int b = 0; b < 8; ++b) { q[4 + b] = r2x[b]; q[12 + b] = r2y[b]; q[20 + b] = t0[b]; }
#pragma unroll
    for (int k = 0; k < 28; ++k) {
        q[k] += __shfl_down(q[k], 32);
        q[k] += __shfl_down(q[k], 16);
    }
    int lane = tid & 63, wv = tid >> 6;
    if (lane < 16) {
#pragma unroll
        for (int k = 0; k < 28; ++k) wred[wv][lane][k] = q[k];
    }
    __syncthreads();
    if (tid < 16) {
        float s[28];
#pragma unroll
        for (int k = 0; k < 28; ++k)
            s[k] = wred[0][tid][k] + wred[1][tid][k] + wred[2][tid][k] + wred[3][tid][k];
        const float invN = 1.0f / 1024.0f;
        float cc[24];
#pragma unroll
        for (int b = 0; b < 8; ++b) {
            float rx = s[4 + b], ry = s[12 + b];
            cc[b] = (64.0f * rx + s[20 + b]) * invN;
            cc[8 + b] = (rx * s[0] - ry * s[1]) * invN;
            cc[16 + b] = (rx * s[2] - ry * s[3]) * (0.5f * invN);
        }
#pragma unroll
        for (int k = 0; k < 24; ++k) {
            cc[k] += __shfl_xor(cc[k], 1);
            cc[k] += __shfl_xor(cc[k], 2);
            cc[k] += __shfl_xor(cc[k], 4);
            cc[k] += __shfl_xor(cc[k], 8);
        }
        if (tid == 0) {
#pragma unroll
            for (int b = 0; b < 8; ++b) {
                c0[b * 64 + o] = cc[b];
                c1[b * 64 + o] = cc[8 + b];
                c2[b * 64 + o] = cc[16 + b];
            }
        }
    }
}

// ---------------- k_gout: fused g + out. 256 blocks x 256 threads.
__global__ __launch_bounds__(256) void k_gout(const float* __restrict__ x,
                                              const float* __restrict__ W0,
                                              const float* __restrict__ b0,
                                              const float* __restrict__ u1,
                                              const float* __restrict__ u2,
                                              const float* __restrict__ WA,
                                              const float* __restrict__ WB,
                                              const float* __restrict__ Wl,
                                              const float* __restrict__ bl,
                                              const float* __restrict__ c0,
                                              const float* __restrict__ c1,
                                              const float* __restrict__ c2,
                                              const float* __restrict__ W1,
                                              const float* __restrict__ b1,
                                              const float* __restrict__ W2,
                                              const float* __restrict__ b2,
                                              float* __restrict__ out) {
    __shared__ float sU1[64 * 32], sU2[64 * 32];                   // [i][n]
    __shared__ float sWl[4096], sWA[4096], sWB[4096], sW1[4096];   // [i][o] / [o][k]
    __shared__ float hhs[64 * 34];                                 // [o][n] pad->34
    __shared__ float sW0a[64], sW0b[64], sb0[64], sbl[64];
    __shared__ float sc0[64], sc1[64], sc2[64], sb1[64], sW2[64];
    __shared__ float red[8 * 32];
    int tid = threadIdx.x;
    int b = blockIdx.x >> 5;
    int n0 = (blockIdx.x & 31) << 5;

    {
        const float4* Wl4 = (const float4*)Wl;
        const float4* WA4 = (const float4*)WA;
        const float4* WB4 = (const float4*)WB;
        const float4* W14 = (const float4*)W1;
        for (int j = tid; j < 1024; j += 256) {
            ((float4*)sWl)[j] = Wl4[j];
            ((float4*)sWA)[j] = WA4[j];
            ((float4*)sWB)[j] = WB4[j];
            ((float4*)sW1)[j] = W14[j];
        }
        const float4* u14 = (const float4*)u1;
        const float4* u24 = (const float4*)u2;
        int nb4 = n0 >> 2;
        for (int j = tid; j < 512; j += 256) {
            int i = j >> 3, c4 = j & 7;
            ((float4*)sU1)[j] = u14[(b * 64 + i) * 256 + nb4 + c4];
            ((float4*)sU2)[j] = u24[(b * 64 + i) * 256 + nb4 + c4];
        }
        if (tid < 64) {
            sW0a[tid] = W0[tid];
            sW0b[tid] = W0[64 + tid];
            sb0[tid] = b0[tid];
            sbl[tid] = bl[tid];
            sc0[tid] = c0[b * 64 + tid];
            sc1[tid] = c1[b * 64 + tid];
            sc2[tid] = c2[b * 64 + tid];
            sb1[tid] = b1[tid];
            sW2[tid] = W2[tid];
        }
    }
    __syncthreads();

    // Phase A: og = tid>>4 (To=4), ng = tid&15 (Tn=2)
    {
        int og = tid >> 4, ng = tid & 15;
        int oB = og * 4, nB = ng * 2;
        float x0a = x[b * 2048 + n0 + nB];
        float x0b = x[b * 2048 + n0 + nB + 1];
        float x1a = x[b * 2048 + 1024 + n0 + nB];
        float x1b = x[b * 2048 + 1024 + n0 + nB + 1];
        float acc0[4], acc1[4];
#pragma unroll
        for (int r = 0; r < 4; ++r) { acc0[r] = 0.f; acc1[r] = 0.f; }
        for (int i = 0; i < 64; ++i) {
            float w0a = sW0a[i], w0b = sW0b[i], bb = sb0[i];
            float hva = x0a * w0a + x1a * w0b + bb;
            float hvb = x0b * w0a + x1b * w0b + bb;
            float2 ua = *(const float2*)&sU1[i * 32 + nB];
            float2 va = *(const float2*)&sU2[i * 32 + nB];
            float4 wl = *(const float4*)&sWl[i * 64 + oB];
            float4 wa = *(const float4*)&sWA[i * 64 + oB];
            float4 wb = *(const float4*)&sWB[i * 64 + oB];
            acc0[0] += hva * wl.x + ua.x * wa.x + va.x * wb.x;
            acc1[0] += hvb * wl.x + ua.y * wa.x + va.y * wb.x;
            acc0[1] += hva * wl.y + ua.x * wa.y + va.x * wb.y;
            acc1[1] += hvb * wl.y + ua.y * wa.y + va.y * wb.y;
            acc0[2] += hva * wl.z + ua.x * wa.z + va.x * wb.z;
            acc1[2] += hvb * wl.z + ua.y * wa.z + va.y * wb.z;
            acc0[3] += hva * wl.w + ua.x * wa.w + va.x * wb.w;
            acc1[3] += hvb * wl.w + ua.y * wa.w + va.y * wb.w;
        }
        float ta = (float)(n0 + nB) * (1.0f / 1023.0f);
        float tb = (float)(n0 + nB + 1) * (1.0f / 1023.0f);
#pragma unroll
        for (int r = 0; r < 4; ++r) {
            int o = oB + r;
            float ga = acc0[r] + sbl[o] + sc0[o] + sc1[o] * ta + sc2[o] * ta * ta;
            float gb = acc1[r] + sbl[o] + sc0[o] + sc1[o] * tb + sc2[o] * tb * tb;
            hhs[o * 34 + nB] = gelu_tanh(ga);
            hhs[o * 34 + nB + 1] = gelu_tanh(gb);
        }
    }
    __syncthreads();

    // Phase B: n = tid&31, kq = tid>>5, k-tile of 8
    {
        int n = tid & 31, kq = tid >> 5;
        float z[8];
#pragma unroll
        for (int k = 0; k < 8; ++k) z[k] = 0.f;
        for (int o = 0; o < 64; ++o) {
            float hv = hhs[o * 34 + n];
            float4 w1a = *(const float4*)&sW1[o * 64 + kq * 8];
            float4 w1b = *(const float4*)&sW1[o * 64 + kq * 8 + 4];
            z[0] += hv * w1a.x; z[1] += hv * w1a.y; z[2] += hv * w1a.z; z[3] += hv * w1a.w;
            z[4] += hv * w1b.x; z[5] += hv * w1b.y; z[6] += hv * w1b.z; z[7] += hv * w1b.w;
        }
        float part = 0.f;
#pragma unroll
        for (int k = 0; k < 8; ++k)
            part += gelu_tanh(z[k] + sb1[kq * 8 + k]) * sW2[kq * 8 + k];
        red[kq * 32 + n] = part;
    }
    __syncthreads();
    if (tid < 32) {
        float s = red[tid];
#pragma unroll
        for (int k = 1; k < 8; ++k) s += red[k * 32 + tid];
        out[b * 1024 + n0 + tid] = s + b2[0];
    }
}

extern "C" void kernel_launch(void* const* d_in, const int* in_sizes, int n_in,
                              void* d_out, int out_size, void* d_ws, size_t ws_size,
                              hipStream_t stream) {
    const float* x = (const float*)d_in[0];
    const float* W0 = (const float*)d_in[1];
    const float* b0 = (const float*)d_in[2];
    const float* wp = (const float*)d_in[3];
    const float* wpi = (const float*)d_in[4];
    const float* wr = (const float*)d_in[5];
    const float* wri = (const float*)d_in[6];
    const float* Wl = (const float*)d_in[7];
    const float* bl = (const float*)d_in[8];
    const float* W1 = (const float*)d_in[9];
    const float* b1 = (const float*)d_in[10];
    const float* W2 = (const float*)d_in[11];
    const float* b2 = (const float*)d_in[12];

    float* ws = (float*)d_ws;
    float* u1 = ws;                    // 524288
    float* u2 = ws + 524288;           // 524288
    float* alpha0 = ws + 1048576;      // 512
    float* A1v = alpha0 + 512;
    float* A2v = alpha0 + 1024;
    float* c0 = alpha0 + 1536;
    float* c1 = alpha0 + 2048;
    float* c2 = alpha0 + 2560;
    float* WA = alpha0 + 3072;         // 4096
    float* WB = alpha0 + 3072 + 4096;  // 4096

    k_main<<<256, 256, 0, stream>>>(x, W0, b0, u1, u2, alpha0, A1v, A2v);
    k_small<<<64, 256, 0, stream>>>(wp, wpi, wr, wri, alpha0, A1v, A2v, WA, WB, c0, c1, c2);
    k_gout<<<256, 256, 0, stream>>>(x, W0, b0, u1, u2, WA, WB, Wl, bl, c0, c1, c2,
                                    W1, b1, W2, b2, (float*)d_out);
}